// Round 4
// baseline (228.785 us; speedup 1.0000x reference)
//
#include <hip/hip_runtime.h>

typedef __bf16 bf16x8 __attribute__((ext_vector_type(8)));
typedef __bf16 bf16x2 __attribute__((ext_vector_type(2)));
typedef float f32x4 __attribute__((ext_vector_type(4)));
typedef unsigned int u32;
typedef u32 u32x4v __attribute__((ext_vector_type(4)));
typedef unsigned short u16;

#define LOG2E 1.44269504088896f

__device__ __forceinline__ u32 pk2(float a, float b){
  bf16x2 v; v[0] = (__bf16)a; v[1] = (__bf16)b;
  return __builtin_bit_cast(u32, v);
}

// ---------------------------------------------------------------------------
// prep_w: build fragment-ordered bf16 weights.
// flat idx = ((cc*24+dt)*64 + lane)*8 + e  ->  W[d = dt*16+(lane&15)][c = cc*32+(lane>>4)*8+e]
// rows 0..63 = w_q, 64..127 = w_k, 128..383 = w_v
// ---------------------------------------------------------------------------
__global__ void prep_w(const float* __restrict__ wq, const float* __restrict__ wk,
                       const float* __restrict__ wv, u16* __restrict__ wfrag){
  int idx  = blockIdx.x * 256 + threadIdx.x;     // < 98304
  int e    = idx & 7;
  int lane = (idx >> 3) & 63;
  int f    = idx >> 9;                           // 0..191
  int cc = f / 24, dt = f % 24;
  int d = dt * 16 + (lane & 15);
  int c = cc * 32 + (lane >> 4) * 8 + e;
  float v;
  if (d < 64)       v = wq[d * 256 + c];
  else if (d < 128) v = wk[(d - 64) * 256 + c];
  else              v = wv[(d - 128) * 256 + c];
  __bf16 h = (__bf16)v;
  wfrag[idx] = __builtin_bit_cast(u16, h);
}

// ---------------------------------------------------------------------------
// proj_kernel v4: 512 threads, 8 waves; wave owns 3 d-tiles x 4 n-tiles
// (acc = 48 VGPR -> 4 waves/SIMD, 2 blocks/CU).  64-n tiles, 32 KB LDS.
//   Q written PRE-SCALED by log2(e), as [B][N][64] bf16 (d contiguous)
//   K written as [B][N][64] bf16
//   V written as [B][256][N] bf16 with each 64-column tile PERMUTED by pi^-1
//     (s = m5 m3 m2 m4 m1 m0) so attn's PV B-fragment needs no P shuffle.
// ---------------------------------------------------------------------------
__launch_bounds__(512, 4)
__global__ void proj_kernel(const float* __restrict__ x,
                            const float* __restrict__ bq, const float* __restrict__ bk,
                            const float* __restrict__ bv,
                            const u16* __restrict__ wfrag,
                            u16* __restrict__ qb, u16* __restrict__ kb, u16* __restrict__ vt)
{
  __shared__ u16 xlds[64 * 256];     // 32 KB, [n][c] rows 512B, 16B-slot swz ^(n&31)
  const int b    = blockIdx.x & 7;
  const int n0   = (blockIdx.x >> 3) * 64;       // 64 n-tiles of 64
  const int t    = threadIdx.x;
  const int lane = t & 63;
  const int w    = t >> 6;                       // 0..7
  const int g    = lane >> 4, j = lane & 15;

  // ---- stage: transpose-convert x[b][:, n0..n0+63] into xlds[n][c] ----
  {
    const int n  = t & 63;
    const int ch = t >> 6;                       // 8 c-groups
    const float* xp = x + ((size_t)b * 256) * 4096 + n0 + n;
    char* lbase = reinterpret_cast<char*>(xlds);
    #pragma unroll
    for (int pass = 0; pass < 4; ++pass){
      int c = pass * 64 + ch * 8;
      float f0 = xp[(size_t)(c+0)*4096], f1 = xp[(size_t)(c+1)*4096];
      float f2 = xp[(size_t)(c+2)*4096], f3 = xp[(size_t)(c+3)*4096];
      float f4 = xp[(size_t)(c+4)*4096], f5 = xp[(size_t)(c+5)*4096];
      float f6 = xp[(size_t)(c+6)*4096], f7 = xp[(size_t)(c+7)*4096];
      uint4 q;
      q.x = pk2(f0, f1); q.y = pk2(f2, f3); q.z = pk2(f4, f5); q.w = pk2(f6, f7);
      u32 off = (u32)n * 512 + (((u32)c * 2) ^ (((u32)n & 31) << 4));
      *reinterpret_cast<uint4*>(lbase + off) = q;
    }
  }
  __syncthreads();

  // ---- GEMM: wave w owns d-tiles dt = w*3 .. w*3+2, 4 n-tiles ----
  f32x4 acc[3][4];
  #pragma unroll
  for (int i = 0; i < 3; ++i)
    #pragma unroll
    for (int nt = 0; nt < 4; ++nt) acc[i][nt] = f32x4{0.f,0.f,0.f,0.f};

  const char* lbase = reinterpret_cast<const char*>(xlds);
  for (int cc = 0; cc < 8; ++cc){
    bf16x8 a[3];
    #pragma unroll
    for (int i = 0; i < 3; ++i)
      a[i] = *reinterpret_cast<const bf16x8*>(wfrag + ((size_t)(cc*24 + w*3 + i) * 64 + lane) * 8);
    bf16x8 bb[4];
    #pragma unroll
    for (int nt = 0; nt < 4; ++nt){
      const u32 row = nt * 16 + j;
      const u32 off = row * 512 + (((u32)(cc * 64 + g * 16)) ^ ((row & 31) << 4));
      bb[nt] = *reinterpret_cast<const bf16x8*>(lbase + off);
    }
    #pragma unroll
    for (int i = 0; i < 3; ++i)
      #pragma unroll
      for (int nt = 0; nt < 4; ++nt)
        acc[i][nt] = __builtin_amdgcn_mfma_f32_16x16x32_bf16(a[i], bb[nt], acc[i][nt], 0, 0, 0);
  }

  // ---- epilogue: bias + convert + store ----
  #pragma unroll
  for (int i = 0; i < 3; ++i){
    const int dt = w * 3 + i;
    const int d0 = dt * 16;
    const int dd = d0 + 4 * g;   // this lane's 4 consecutive d rows
    if (d0 < 64){
      float b0 = bq[dd], b1 = bq[dd+1], b2 = bq[dd+2], b3 = bq[dd+3];
      #pragma unroll
      for (int nt = 0; nt < 4; ++nt){
        const int n = n0 + nt * 16 + j;
        uint2 u;
        u.x = pk2((acc[i][nt][0] + b0) * LOG2E, (acc[i][nt][1] + b1) * LOG2E);
        u.y = pk2((acc[i][nt][2] + b2) * LOG2E, (acc[i][nt][3] + b3) * LOG2E);
        *reinterpret_cast<uint2*>(qb + ((size_t)b * 4096 + n) * 64 + dd) = u;
      }
    } else if (d0 < 128){
      const int dk = dd - 64;
      float b0 = bk[dk], b1 = bk[dk+1], b2 = bk[dk+2], b3 = bk[dk+3];
      #pragma unroll
      for (int nt = 0; nt < 4; ++nt){
        const int n = n0 + nt * 16 + j;
        uint2 u;
        u.x = pk2(acc[i][nt][0] + b0, acc[i][nt][1] + b1);
        u.y = pk2(acc[i][nt][2] + b2, acc[i][nt][3] + b3);
        *reinterpret_cast<uint2*>(kb + ((size_t)b * 4096 + n) * 64 + dk) = u;
      }
    } else {
      const int dv = dd - 128;
      float b0 = bv[dv], b1 = bv[dv+1], b2 = bv[dv+2], b3 = bv[dv+3];
      #pragma unroll
      for (int nt = 0; nt < 4; ++nt){
        // permuted column: s = m5 m3 m2 m4 m1 m0, m = nt*16 + j
        const int scol = ((nt & 2) << 4) | ((j & 12) << 1) | ((nt & 1) << 2) | (j & 3);
        const int n = n0 + scol;
        u16* vp = vt + (size_t)b * 256 * 4096 + n;
        __bf16 h0 = (__bf16)(acc[i][nt][0] + b0);
        __bf16 h1 = (__bf16)(acc[i][nt][1] + b1);
        __bf16 h2 = (__bf16)(acc[i][nt][2] + b2);
        __bf16 h3 = (__bf16)(acc[i][nt][3] + b3);
        vp[(size_t)(dv+0) * 4096] = __builtin_bit_cast(u16, h0);
        vp[(size_t)(dv+1) * 4096] = __builtin_bit_cast(u16, h1);
        vp[(size_t)(dv+2) * 4096] = __builtin_bit_cast(u16, h2);
        vp[(size_t)(dv+3) * 4096] = __builtin_bit_cast(u16, h3);
      }
    }
  }
}

// ---------------------------------------------------------------------------
// attn_kernel v4: 512 blocks x 8 waves (512 thr). Block = 64 q-rows x 256 dv.
// Wave = (col-quarter w&3: 16 q-cols) x (dv-half w>>2: 128 dv).
// Same grid/LDS/barriers/MFMA-totals as v3, but 16 waves/CU (4/SIMD) so the
// serial softmax chain hides under other waves' MFMA.
// In-register P via m-permuted V. Defer-max THR=8. pf via v_cvt_pk.
// ---------------------------------------------------------------------------
__launch_bounds__(512, 4)
__global__ void attn_kernel(const u16* __restrict__ qb, const u16* __restrict__ kb,
                            const u16* __restrict__ vt, float* __restrict__ out)
{
  __shared__ u16 kl[2][64 * 64];     // 16 KB  K tile [m][d], rows 128B, swz (m&7)<<4
  __shared__ u16 vl[2][256 * 64];    // 64 KB  V^T tile [dv][s], rows 128B, swz (dv&7)<<4

  const int b    = blockIdx.x & 7;
  const int qc   = blockIdx.x >> 3;            // 0..63
  const int t    = threadIdx.x, lane = t & 63, w = t >> 6;   // w: 0..7
  const int g    = lane >> 4, j = lane & 15;
  const int colq = w & 3;                      // 16-col group
  const int dvh  = (w >> 2) * 128;             // dv-half base

  const u16* Kg = kb + (size_t)b * 4096 * 64;
  const u16* Vg = vt + (size_t)b * 256 * 4096;

  // Q fragments (persistent, pre-scaled by log2e)
  const u16* Qrow = qb + ((size_t)b * 4096 + qc * 64 + colq * 16 + j) * 64;
  const bf16x8 qf0 = *reinterpret_cast<const bf16x8*>(Qrow + 8 * g);
  const bf16x8 qf1 = *reinterpret_cast<const bf16x8*>(Qrow + 32 + 8 * g);

  f32x4 o[8];
  #pragma unroll
  for (int i = 0; i < 8; ++i) o[i] = f32x4{0.f,0.f,0.f,0.f};
  float mrun = -1.0e30f, lrun = 0.f;

  auto stage = [&](int tile, int buf){
    const int m0 = tile * 64;
    {                                          // K tile: 64 rows x 128B, 1 load/wave
      const int r = w * 8 + (lane >> 3);
      const char* src = reinterpret_cast<const char*>(Kg + (size_t)(m0 + r) * 64)
                        + ((((u32)lane & 7) * 16) ^ ((((u32)r) & 7) << 4));
      char* dst = reinterpret_cast<char*>(&kl[buf][0]) + w * 1024;
      __builtin_amdgcn_global_load_lds((const __attribute__((address_space(1))) void*)src,
                                       (__attribute__((address_space(3))) void*)dst, 16, 0, 0);
    }
    #pragma unroll
    for (int i = 0; i < 4; ++i){               // V^T tile: 256 rows x 128B, 4 loads/wave
      const int dv = i * 64 + w * 8 + (lane >> 3);
      const char* src = reinterpret_cast<const char*>(Vg + (size_t)dv * 4096 + m0)
                        + ((((u32)lane & 7) * 16) ^ (((u32)dv & 7) << 4));
      char* dst = reinterpret_cast<char*>(&vl[buf][0]) + i * 8192 + w * 1024;
      __builtin_amdgcn_global_load_lds((const __attribute__((address_space(1))) void*)src,
                                       (__attribute__((address_space(3))) void*)dst, 16, 0, 0);
    }
  };

  stage(0, 0);
  __syncthreads();

  const u32 vsw = ((u32)j & 7) << 4;   // V read swizzle (dv&7 == j&7, loop-invariant)

  for (int tile = 0; tile < 64; ++tile){
    const int cur = tile & 1;
    if (tile + 1 < 64) stage(tile + 1, cur ^ 1);

    const char* kbase = reinterpret_cast<const char*>(&kl[cur][0]);
    const char* vbase = reinterpret_cast<const char*>(&vl[cur][0]);

    // ---- S^T tile: s[mt][r] = S2[m=16mt+4g+r][n = colq*16+j], log2 domain ----
    f32x4 s[4];
    __builtin_amdgcn_s_setprio(1);
    #pragma unroll
    for (int mt = 0; mt < 4; ++mt){
      const u32 row = mt * 16 + j;
      const u32 sw  = (row & 7) << 4;
      bf16x8 ka0 = *reinterpret_cast<const bf16x8*>(kbase + row * 128 + (((u32)(g * 16)) ^ sw));
      bf16x8 ka1 = *reinterpret_cast<const bf16x8*>(kbase + row * 128 + (((u32)(64 + g * 16)) ^ sw));
      f32x4 z = f32x4{0.f,0.f,0.f,0.f};
      z = __builtin_amdgcn_mfma_f32_16x16x32_bf16(ka0, qf0, z, 0, 0, 0);
      z = __builtin_amdgcn_mfma_f32_16x16x32_bf16(ka1, qf1, z, 0, 0, 0);
      s[mt] = z;
    }
    __builtin_amdgcn_s_setprio(0);

    // ---- online softmax (base-2; column n lane-local; reduce over g) ----
    float pmax = s[0][0];
    #pragma unroll
    for (int mt = 0; mt < 4; ++mt)
      #pragma unroll
      for (int r = 0; r < 4; ++r) pmax = fmaxf(pmax, s[mt][r]);
    pmax = fmaxf(pmax, __shfl_xor(pmax, 16));
    pmax = fmaxf(pmax, __shfl_xor(pmax, 32));

    // defer-max: rescale only when some row's max grew past mrun + 8
    if (__any(pmax > mrun + 8.0f)){
      const float mnew  = fmaxf(mrun, pmax);
      const float alpha = __builtin_amdgcn_exp2f(mrun - mnew);
      mrun = mnew;
      lrun *= alpha;
      #pragma unroll
      for (int i = 0; i < 8; ++i){
        o[i][0] *= alpha; o[i][1] *= alpha; o[i][2] *= alpha; o[i][3] *= alpha;
      }
    }

    float psum = 0.f;
    u32 pw[8];
    #pragma unroll
    for (int mt = 0; mt < 4; ++mt){
      float p0 = __builtin_amdgcn_exp2f(s[mt][0] - mrun);
      float p1 = __builtin_amdgcn_exp2f(s[mt][1] - mrun);
      float p2 = __builtin_amdgcn_exp2f(s[mt][2] - mrun);
      float p3 = __builtin_amdgcn_exp2f(s[mt][3] - mrun);
      psum += (p0 + p1) + (p2 + p3);
      pw[2*mt]   = pk2(p0, p1);
      pw[2*mt+1] = pk2(p2, p3);
    }
    psum += __shfl_xor(psum, 16);
    psum += __shfl_xor(psum, 32);
    lrun += psum;

    // ---- PV: O^T[dv][n] += V^T[dv][s] * P[s][n] ; pw IS the B-fragment ----
    __builtin_amdgcn_s_setprio(1);
    #pragma unroll
    for (int mc = 0; mc < 2; ++mc){
      u32x4v pv = { pw[4*mc+0], pw[4*mc+1], pw[4*mc+2], pw[4*mc+3] };
      bf16x8 pf = __builtin_bit_cast(bf16x8, pv);
      #pragma unroll
      for (int dt = 0; dt < 8; ++dt){
        const u32 dv = dvh + dt * 16 + j;
        bf16x8 vf = *reinterpret_cast<const bf16x8*>(vbase + dv * 128 + (((u32)(mc * 64 + 16 * g)) ^ vsw));
        o[dt] = __builtin_amdgcn_mfma_f32_16x16x32_bf16(vf, pf, o[dt], 0, 0, 0);
      }
    }
    __builtin_amdgcn_s_setprio(0);

    __syncthreads();
  }

  // ---- epilogue: divide by l, store O^T coalesced ----
  const float rinv = 1.0f / lrun;
  const int n = qc * 64 + colq * 16 + j;
  float* ob = out + (size_t)b * 256 * 4096 + n;
  #pragma unroll
  for (int dt = 0; dt < 8; ++dt){
    const int dv0 = dvh + dt * 16 + 4 * g;
    #pragma unroll
    for (int r = 0; r < 4; ++r)
      ob[(size_t)(dv0 + r) * 4096] = o[dt][r] * rinv;
  }
}

// ---------------------------------------------------------------------------
extern "C" void kernel_launch(void* const* d_in, const int* in_sizes, int n_in,
                              void* d_out, int out_size, void* d_ws, size_t ws_size,
                              hipStream_t stream)
{
  (void)in_sizes; (void)n_in; (void)out_size; (void)ws_size;
  const float* x  = (const float*)d_in[0];
  const float* wq = (const float*)d_in[1];
  const float* bq = (const float*)d_in[2];
  const float* wk = (const float*)d_in[3];
  const float* bk = (const float*)d_in[4];
  const float* wv = (const float*)d_in[5];
  const float* bv = (const float*)d_in[6];
  float* out = (float*)d_out;

  char* ws = (char*)d_ws;
  u16* qbuf  = (u16*)(ws + 0);            //  4 MB  [8][4096][64]  (pre-scaled by log2e)
  u16* kbuf  = (u16*)(ws + 4194304);      //  4 MB  [8][4096][64]
  u16* vbuf  = (u16*)(ws + 8388608);      // 16 MB  [8][256][4096] (m-permuted per 64-tile)
  u16* wfrag = (u16*)(ws + 25165824);     // 192 KB

  prep_w<<<dim3(384), dim3(256), 0, stream>>>(wq, wk, wv, wfrag);
  proj_kernel<<<dim3(512), dim3(512), 0, stream>>>(x, bq, bk, bv, wfrag, qbuf, kbuf, vbuf);
  attn_kernel<<<dim3(512), dim3(512), 0, stream>>>(qbuf, kbuf, vbuf, out);
}

// Round 5
// 227.555 us; speedup vs baseline: 1.0054x; 1.0054x over previous
//
#include <hip/hip_runtime.h>

typedef __bf16 bf16x8 __attribute__((ext_vector_type(8)));
typedef __bf16 bf16x2 __attribute__((ext_vector_type(2)));
typedef float f32x4 __attribute__((ext_vector_type(4)));
typedef float f32x16 __attribute__((ext_vector_type(16)));
typedef unsigned int u32;
typedef u32 u32x4v __attribute__((ext_vector_type(4)));
typedef unsigned short u16;

#define LOG2E 1.44269504088896f

__device__ __forceinline__ u32 pk2(float a, float b){
  bf16x2 v; v[0] = (__bf16)a; v[1] = (__bf16)b;
  return __builtin_bit_cast(u32, v);
}

// ---------------------------------------------------------------------------
// prep_w: build fragment-ordered bf16 weights (16x16x32 A-frag layout).
// flat idx = ((cc*24+dt)*64 + lane)*8 + e  ->  W[d = dt*16+(lane&15)][c = cc*32+(lane>>4)*8+e]
// ---------------------------------------------------------------------------
__global__ void prep_w(const float* __restrict__ wq, const float* __restrict__ wk,
                       const float* __restrict__ wv, u16* __restrict__ wfrag){
  int idx  = blockIdx.x * 256 + threadIdx.x;     // < 98304
  int e    = idx & 7;
  int lane = (idx >> 3) & 63;
  int f    = idx >> 9;                           // 0..191
  int cc = f / 24, dt = f % 24;
  int d = dt * 16 + (lane & 15);
  int c = cc * 32 + (lane >> 4) * 8 + e;
  float v;
  if (d < 64)       v = wq[d * 256 + c];
  else if (d < 128) v = wk[(d - 64) * 256 + c];
  else              v = wv[(d - 128) * 256 + c];
  __bf16 h = (__bf16)v;
  wfrag[idx] = __builtin_bit_cast(u16, h);
}

// ---------------------------------------------------------------------------
// proj_kernel: Out[d][n] = sum_c W[d][c] x[b][c][n] + bias.  64-n tiles.
//   Q PRE-SCALED by log2(e), [B][N][64] bf16 (d contiguous)
//   K [B][N][64] bf16
//   V [B][256][N] bf16, each 64-column tile permuted by the NEW pi for the
//     32x32 MFMA path: s = (m0, m1, m3, m2, m4, m5)  (s2<->s3 swap of m bits)
// ---------------------------------------------------------------------------
__launch_bounds__(512, 4)
__global__ void proj_kernel(const float* __restrict__ x,
                            const float* __restrict__ bq, const float* __restrict__ bk,
                            const float* __restrict__ bv,
                            const u16* __restrict__ wfrag,
                            u16* __restrict__ qb, u16* __restrict__ kb, u16* __restrict__ vt)
{
  __shared__ u16 xlds[64 * 256];     // 32 KB, [n][c] rows 512B, 16B-slot swz ^(n&31)
  const int b    = blockIdx.x & 7;
  const int n0   = (blockIdx.x >> 3) * 64;       // 64 n-tiles of 64
  const int t    = threadIdx.x;
  const int lane = t & 63;
  const int w    = t >> 6;                       // 0..7
  const int g    = lane >> 4, j = lane & 15;

  // ---- stage: transpose-convert x[b][:, n0..n0+63] into xlds[n][c] ----
  {
    const int n  = t & 63;
    const int ch = t >> 6;                       // 8 c-groups
    const float* xp = x + ((size_t)b * 256) * 4096 + n0 + n;
    char* lbase = reinterpret_cast<char*>(xlds);
    #pragma unroll
    for (int pass = 0; pass < 4; ++pass){
      int c = pass * 64 + ch * 8;
      float f0 = xp[(size_t)(c+0)*4096], f1 = xp[(size_t)(c+1)*4096];
      float f2 = xp[(size_t)(c+2)*4096], f3 = xp[(size_t)(c+3)*4096];
      float f4 = xp[(size_t)(c+4)*4096], f5 = xp[(size_t)(c+5)*4096];
      float f6 = xp[(size_t)(c+6)*4096], f7 = xp[(size_t)(c+7)*4096];
      uint4 q;
      q.x = pk2(f0, f1); q.y = pk2(f2, f3); q.z = pk2(f4, f5); q.w = pk2(f6, f7);
      u32 off = (u32)n * 512 + (((u32)c * 2) ^ (((u32)n & 31) << 4));
      *reinterpret_cast<uint4*>(lbase + off) = q;
    }
  }
  __syncthreads();

  // ---- GEMM: wave w owns d-tiles dt = w*3 .. w*3+2, 4 n-tiles ----
  f32x4 acc[3][4];
  #pragma unroll
  for (int i = 0; i < 3; ++i)
    #pragma unroll
    for (int nt = 0; nt < 4; ++nt) acc[i][nt] = f32x4{0.f,0.f,0.f,0.f};

  const char* lbase = reinterpret_cast<const char*>(xlds);
  for (int cc = 0; cc < 8; ++cc){
    bf16x8 a[3];
    #pragma unroll
    for (int i = 0; i < 3; ++i)
      a[i] = *reinterpret_cast<const bf16x8*>(wfrag + ((size_t)(cc*24 + w*3 + i) * 64 + lane) * 8);
    bf16x8 bb[4];
    #pragma unroll
    for (int nt = 0; nt < 4; ++nt){
      const u32 row = nt * 16 + j;
      const u32 off = row * 512 + (((u32)(cc * 64 + g * 16)) ^ ((row & 31) << 4));
      bb[nt] = *reinterpret_cast<const bf16x8*>(lbase + off);
    }
    #pragma unroll
    for (int i = 0; i < 3; ++i)
      #pragma unroll
      for (int nt = 0; nt < 4; ++nt)
        acc[i][nt] = __builtin_amdgcn_mfma_f32_16x16x32_bf16(a[i], bb[nt], acc[i][nt], 0, 0, 0);
  }

  // ---- epilogue: bias + convert + store ----
  #pragma unroll
  for (int i = 0; i < 3; ++i){
    const int dt = w * 3 + i;
    const int d0 = dt * 16;
    const int dd = d0 + 4 * g;   // this lane's 4 consecutive d rows
    if (d0 < 64){
      float b0 = bq[dd], b1 = bq[dd+1], b2 = bq[dd+2], b3 = bq[dd+3];
      #pragma unroll
      for (int nt = 0; nt < 4; ++nt){
        const int n = n0 + nt * 16 + j;
        uint2 u;
        u.x = pk2((acc[i][nt][0] + b0) * LOG2E, (acc[i][nt][1] + b1) * LOG2E);
        u.y = pk2((acc[i][nt][2] + b2) * LOG2E, (acc[i][nt][3] + b3) * LOG2E);
        *reinterpret_cast<uint2*>(qb + ((size_t)b * 4096 + n) * 64 + dd) = u;
      }
    } else if (d0 < 128){
      const int dk = dd - 64;
      float b0 = bk[dk], b1 = bk[dk+1], b2 = bk[dk+2], b3 = bk[dk+3];
      #pragma unroll
      for (int nt = 0; nt < 4; ++nt){
        const int n = n0 + nt * 16 + j;
        uint2 u;
        u.x = pk2(acc[i][nt][0] + b0, acc[i][nt][1] + b1);
        u.y = pk2(acc[i][nt][2] + b2, acc[i][nt][3] + b3);
        *reinterpret_cast<uint2*>(kb + ((size_t)b * 4096 + n) * 64 + dk) = u;
      }
    } else {
      const int dv = dd - 128;
      float b0 = bv[dv], b1 = bv[dv+1], b2 = bv[dv+2], b3 = bv[dv+3];
      #pragma unroll
      for (int nt = 0; nt < 4; ++nt){
        // NEW permutation: m = nt*16+j ; s = m0,m1,m3,m2,m4,m5
        const int scol = (nt << 4) | ((j & 8) >> 1) | ((j & 4) << 1) | (j & 3);
        const int n = n0 + scol;
        u16* vp = vt + (size_t)b * 256 * 4096 + n;
        __bf16 h0 = (__bf16)(acc[i][nt][0] + b0);
        __bf16 h1 = (__bf16)(acc[i][nt][1] + b1);
        __bf16 h2 = (__bf16)(acc[i][nt][2] + b2);
        __bf16 h3 = (__bf16)(acc[i][nt][3] + b3);
        vp[(size_t)(dv+0) * 4096] = __builtin_bit_cast(u16, h0);
        vp[(size_t)(dv+1) * 4096] = __builtin_bit_cast(u16, h1);
        vp[(size_t)(dv+2) * 4096] = __builtin_bit_cast(u16, h2);
        vp[(size_t)(dv+3) * 4096] = __builtin_bit_cast(u16, h3);
      }
    }
  }
}

// ---------------------------------------------------------------------------
// attn_kernel v5: 32x32x16 MFMA (2x FLOP per LDS byte vs 16x16x32).
// 512 blocks x 4 waves (256 thr). Block = 64 q-rows x 256 dv; wave =
// (colg w&1: 32 q-cols) x (dvh w>>1: 128 dv). 2 blocks/CU, 80 KB LDS.
// S^T = mfma32(K, Q): C col = lane&31 = q-col (lane-local softmax, 1 shfl).
// P values in C-regs ARE the PV B-frags (V stored with s = m0,m1,m3,m2,m4,m5):
//   pf[c][e] = p[c>>1][e + 8*(c&1)]  -- pure register renaming.
// ---------------------------------------------------------------------------
__launch_bounds__(256, 2)
__global__ void attn_kernel(const u16* __restrict__ qb, const u16* __restrict__ kb,
                            const u16* __restrict__ vt, float* __restrict__ out)
{
  __shared__ u16 kl[2][64 * 64];     // 16 KB  K tile [m][d], rows 128B, swz (m&7)<<4
  __shared__ u16 vl[2][256 * 64];    // 64 KB  V^T tile [dv][s], rows 128B, swz (dv&7)<<4

  const int b    = blockIdx.x & 7;
  const int qc   = blockIdx.x >> 3;            // 0..63
  const int t    = threadIdx.x, lane = t & 63, w = t >> 6;   // w: 0..3
  const int i32l = lane & 31, hi = lane >> 5;
  const int colg = w & 1;                      // 32-col group
  const int dvh  = (w >> 1) * 128;             // dv-half base

  const u16* Kg = kb + (size_t)b * 4096 * 64;
  const u16* Vg = vt + (size_t)b * 256 * 4096;

  // Q fragments (pre-scaled by log2e): B[k][j]: j = i32l, k = 16*kc + 8*hi + e
  const u16* Qrow = qb + ((size_t)b * 4096 + qc * 64 + colg * 32 + i32l) * 64;
  bf16x8 qf[4];
  #pragma unroll
  for (int kc = 0; kc < 4; ++kc)
    qf[kc] = *reinterpret_cast<const bf16x8*>(Qrow + kc * 16 + hi * 8);

  f32x16 o[4];
  #pragma unroll
  for (int ds = 0; ds < 4; ++ds)
    #pragma unroll
    for (int r = 0; r < 16; ++r) o[ds][r] = 0.f;
  float mrun = -1.0e30f, lrun = 0.f;

  auto stage = [&](int tile, int buf){
    const int m0 = tile * 64;
    #pragma unroll
    for (int i = 0; i < 2; ++i){             // K tile: 64 rows x 128B
      const int r = i * 32 + w * 8 + (lane >> 3);
      const char* src = reinterpret_cast<const char*>(Kg + (size_t)(m0 + r) * 64)
                        + ((((u32)lane & 7) * 16) ^ ((((u32)r) & 7) << 4));
      char* dst = reinterpret_cast<char*>(&kl[buf][0]) + i * 4096 + w * 1024;
      __builtin_amdgcn_global_load_lds((const __attribute__((address_space(1))) void*)src,
                                       (__attribute__((address_space(3))) void*)dst, 16, 0, 0);
    }
    #pragma unroll
    for (int i = 0; i < 8; ++i){             // V^T tile: 256 rows x 128B
      const int dv = i * 32 + w * 8 + (lane >> 3);
      const char* src = reinterpret_cast<const char*>(Vg + (size_t)dv * 4096 + m0)
                        + ((((u32)lane & 7) * 16) ^ (((u32)dv & 7) << 4));
      char* dst = reinterpret_cast<char*>(&vl[buf][0]) + i * 4096 + w * 1024;
      __builtin_amdgcn_global_load_lds((const __attribute__((address_space(1))) void*)src,
                                       (__attribute__((address_space(3))) void*)dst, 16, 0, 0);
    }
  };

  stage(0, 0);
  __syncthreads();

  const u32 swk   = ((u32)i32l & 7) << 4;    // row&7 swizzle (K rows & V rows == i32l mod 8)
  const u32 r0off = (u32)i32l * 128;

  for (int tile = 0; tile < 64; ++tile){
    const int cur = tile & 1;
    if (tile + 1 < 64) stage(tile + 1, cur ^ 1);

    const char* kbase = reinterpret_cast<const char*>(&kl[cur][0]);
    const char* vbase = reinterpret_cast<const char*>(&vl[cur][0]);

    // ---- S^T: two 32x32 subtiles (m in [0,32) and [32,64)), K=64 chained ----
    f32x16 s0, s1;
    #pragma unroll
    for (int r = 0; r < 16; ++r){ s0[r] = 0.f; s1[r] = 0.f; }
    __builtin_amdgcn_s_setprio(1);
    #pragma unroll
    for (int kc = 0; kc < 4; ++kc){
      const u32 cb = ((u32)(kc * 32 + hi * 16)) ^ swk;
      bf16x8 ka0 = *reinterpret_cast<const bf16x8*>(kbase + r0off + cb);
      bf16x8 ka1 = *reinterpret_cast<const bf16x8*>(kbase + 4096 + r0off + cb);
      s0 = __builtin_amdgcn_mfma_f32_32x32x16_bf16(ka0, qf[kc], s0, 0, 0, 0);
      s1 = __builtin_amdgcn_mfma_f32_32x32x16_bf16(ka1, qf[kc], s1, 0, 0, 0);
    }
    __builtin_amdgcn_s_setprio(0);
    // lane holds col n = colg*32+i32l; rows m = 32*t + (r&3)+8*(r>>2)+4*hi

    // ---- online softmax (base-2); in-lane tree over 32 + shfl_xor(32) ----
    float mx[8];
    #pragma unroll
    for (int r = 0; r < 8; ++r)
      mx[r] = fmaxf(fmaxf(s0[r], s0[r+8]), fmaxf(s1[r], s1[r+8]));
    float pmax = fmaxf(fmaxf(fmaxf(mx[0],mx[1]), fmaxf(mx[2],mx[3])),
                       fmaxf(fmaxf(mx[4],mx[5]), fmaxf(mx[6],mx[7])));
    pmax = fmaxf(pmax, __shfl_xor(pmax, 32));

    // defer-max: rescale only when some col's max grew past mrun + 8
    if (__any(pmax > mrun + 8.0f)){
      const float mnew  = fmaxf(mrun, pmax);
      const float alpha = __builtin_amdgcn_exp2f(mrun - mnew);
      mrun = mnew;
      lrun *= alpha;
      #pragma unroll
      for (int ds = 0; ds < 4; ++ds)
        #pragma unroll
        for (int r = 0; r < 16; ++r) o[ds][r] *= alpha;
    }

    float p0[16], p1[16];
    #pragma unroll
    for (int r = 0; r < 16; ++r){
      p0[r] = __builtin_amdgcn_exp2f(s0[r] - mrun);
      p1[r] = __builtin_amdgcn_exp2f(s1[r] - mrun);
    }
    float a8[8];
    #pragma unroll
    for (int r = 0; r < 8; ++r) a8[r] = (p0[r] + p0[r+8]) + (p1[r] + p1[r+8]);
    float ps = ((a8[0]+a8[1]) + (a8[2]+a8[3])) + ((a8[4]+a8[5]) + (a8[6]+a8[7]));
    ps += __shfl_xor(ps, 32);
    lrun += ps;

    // ---- pack P into PV B-frags: pf[c][e] = p[c>>1][e + 8*(c&1)] ----
    u32x4v w0 = { pk2(p0[0],p0[1]),  pk2(p0[2],p0[3]),  pk2(p0[4],p0[5]),  pk2(p0[6],p0[7]) };
    u32x4v w1 = { pk2(p0[8],p0[9]),  pk2(p0[10],p0[11]),pk2(p0[12],p0[13]),pk2(p0[14],p0[15]) };
    u32x4v w2 = { pk2(p1[0],p1[1]),  pk2(p1[2],p1[3]),  pk2(p1[4],p1[5]),  pk2(p1[6],p1[7]) };
    u32x4v w3 = { pk2(p1[8],p1[9]),  pk2(p1[10],p1[11]),pk2(p1[12],p1[13]),pk2(p1[14],p1[15]) };
    bf16x8 pf[4] = { __builtin_bit_cast(bf16x8, w0), __builtin_bit_cast(bf16x8, w1),
                     __builtin_bit_cast(bf16x8, w2), __builtin_bit_cast(bf16x8, w3) };

    // ---- PV: O^T[dv][n] += V^T[dv][s] * P[s][n] ----
    __builtin_amdgcn_s_setprio(1);
    #pragma unroll
    for (int c = 0; c < 4; ++c){
      const u32 cb = ((u32)(c * 32 + hi * 16)) ^ swk;
      #pragma unroll
      for (int ds = 0; ds < 4; ++ds){
        const u32 voff = (u32)(dvh + ds * 32) * 128 + r0off + cb;
        bf16x8 vf = *reinterpret_cast<const bf16x8*>(vbase + voff);
        o[ds] = __builtin_amdgcn_mfma_f32_32x32x16_bf16(vf, pf[c], o[ds], 0, 0, 0);
      }
    }
    __builtin_amdgcn_s_setprio(0);

    __syncthreads();
  }

  // ---- epilogue: divide by l, store O^T (32-lane row-contiguous) ----
  const float rinv = 1.0f / lrun;
  const int n = qc * 64 + colg * 32 + i32l;
  float* ob = out + (size_t)b * 256 * 4096 + n;
  #pragma unroll
  for (int ds = 0; ds < 4; ++ds){
    #pragma unroll
    for (int r = 0; r < 16; ++r){
      const int dv = dvh + ds * 32 + (r & 3) + 8 * (r >> 2) + 4 * hi;
      ob[(size_t)dv * 4096] = o[ds][r] * rinv;
    }
  }
}

// ---------------------------------------------------------------------------
extern "C" void kernel_launch(void* const* d_in, const int* in_sizes, int n_in,
                              void* d_out, int out_size, void* d_ws, size_t ws_size,
                              hipStream_t stream)
{
  (void)in_sizes; (void)n_in; (void)out_size; (void)ws_size;
  const float* x  = (const float*)d_in[0];
  const float* wq = (const float*)d_in[1];
  const float* bq = (const float*)d_in[2];
  const float* wk = (const float*)d_in[3];
  const float* bk = (const float*)d_in[4];
  const float* wv = (const float*)d_in[5];
  const float* bv = (const float*)d_in[6];
  float* out = (float*)d_out;

  char* ws = (char*)d_ws;
  u16* qbuf  = (u16*)(ws + 0);            //  4 MB  [8][4096][64]  (pre-scaled by log2e)
  u16* kbuf  = (u16*)(ws + 4194304);      //  4 MB  [8][4096][64]
  u16* vbuf  = (u16*)(ws + 8388608);      // 16 MB  [8][256][4096] (pi-permuted per 64-tile)
  u16* wfrag = (u16*)(ws + 25165824);     // 192 KB

  prep_w<<<dim3(384), dim3(256), 0, stream>>>(wq, wk, wv, wfrag);
  proj_kernel<<<dim3(512), dim3(512), 0, stream>>>(x, bq, bk, bv, wfrag, qbuf, kbuf, vbuf);
  attn_kernel<<<dim3(512), dim3(256), 0, stream>>>(qbuf, kbuf, vbuf, out);
}